// Round 5
// baseline (107.632 us; speedup 1.0000x reference)
//
#include <hip/hip_runtime.h>
#include <float.h>

#define POOL 7
#define FW 2048
#define FH 2048
#define CROP 96
#define LROW 100                    // floats per LDS row (25 float4)
#define LDSPAD 104                  // over-read margin for unrolled 5-vec col reads

// One block per box.
//  Stage ch0 window (rows < h, float4 groups < wvec) -> regs -> LDS.
//  Bin-max with COMPILE-TIME bounds: 4 predicated rows x 5 predicated float4
//  groups per lane (4 lanes/output, shfl combine) -> one lgkmcnt wait, no
//  serial load-use chain. ch1 global loads fly during ch0 bin-max.
//  FC weights/bias/boxes prefetched at entry. 98->4 FC + ReLU + add.
__global__ __launch_bounds__(256, 4) void roi_pool_fc_kernel(
    const float* __restrict__ feature,   // [2, 2048, 2048]
    const float* __restrict__ boxes,     // [N, 6]
    const int*   __restrict__ coords,    // [N, 4] (y1, x1, y2, x2)
    const float* __restrict__ fc_w,      // [4, 98]
    const float* __restrict__ fc_b,      // [4]
    float* __restrict__ out,             // [N, 6]
    int N)
{
    const int n = blockIdx.x;
    const int t = threadIdx.x;

    __shared__ float lds[CROP * LROW + LDSPAD];   // 38,816 B -> 4 blocks/CU
    __shared__ float pooled[98];                  // channel-major: c*49 + i*7 + j
    __shared__ float delta[4];

    const int4 cd = ((const int4*)coords)[n];
    const int y1 = cd.x;
    const int x1 = cd.y;
    const int h  = cd.z - y1;   // 7 <= h <= 96
    const int w  = cd.w - x1;   // 7 <= w <= 96

    // ---- early prefetches (independent of feature staging; latency hidden)
    float wpre[4] = {0.f, 0.f, 0.f, 0.f};
    float bias = 0.f;
    if (t < 128) {
        const int oo = t >> 5, lane = t & 31;
        const float* wrow = fc_w + oo * 98;
        #pragma unroll
        for (int k = 0; k < 4; ++k) {
            const int idx = lane + 32 * k;
            if (idx < 98) wpre[k] = wrow[idx];
        }
        if (lane == 0) bias = fc_b[oo];
    }
    const float bx = (t < 6) ? boxes[n * 6 + t] : 0.f;

    const int x1a  = x1 & ~3;              // 16B-aligned window start
    const int off  = x1 - x1a;             // 0..3
    const int wvec = (w + off + 3) >> 2;   // float4 groups needed per row

    // Compute-phase mapping: t -> (output o, row-split slot s)
    const int o = t >> 2;           // 0..48 for t < 196
    const int s = t & 3;
    const int i = o / 7;
    const int j = o % 7;
    int sr = 0, er = 0, sc = 0, ec = 0, sc4 = 0;
    if (t < 196) {
        sr  = (i * h) / POOL;
        er  = ((i + 1) * h + POOL - 1) / POOL;          // er <= h <= 96
        sc  = (j * w) / POOL + off;
        ec  = ((j + 1) * w + POOL - 1) / POOL + off;    // ec - sc <= 14
        sc4 = sc >> 2;                                  // sc4 <= 21
    }

    // Unrolled predicated bin-max: 4 rows x 5 float4 groups, one wait.
    auto binmax = [&]() -> float {
        float m = -FLT_MAX;
        #pragma unroll
        for (int k = 0; k < 4; ++k) {
            const int r = sr + s + 4 * k;
            const bool rok = r < er;                    // er<=96 -> safe row < 96
            const float4* rowp = (const float4*)(lds + (rok ? r : 0) * LROW);
            float pm = -FLT_MAX;
            #pragma unroll
            for (int q = 0; q < 5; ++q) {
                const float4 v = rowp[sc4 + q];         // may touch pad: masked below
                const int b = (sc4 + q) * 4;
                pm = fmaxf(pm, (b + 0 >= sc && b + 0 < ec) ? v.x : -FLT_MAX);
                pm = fmaxf(pm, (b + 1 >= sc && b + 1 < ec) ? v.y : -FLT_MAX);
                pm = fmaxf(pm, (b + 2 >= sc && b + 2 < ec) ? v.z : -FLT_MAX);
                pm = fmaxf(pm, (b + 3 >= sc && b + 3 < ec) ? v.w : -FLT_MAX);
            }
            m = rok ? fmaxf(m, pm) : m;
        }
        m = fmaxf(m, __shfl_xor(m, 1, 64));             // combine 4 row-split lanes
        m = fmaxf(m, __shfl_xor(m, 2, 64));
        return m;
    };

    // ---- staging geometry: up to 96 rows x 25 float4 = 2400 vecs; 10 x 256
    const float* b0 = feature + (size_t)y1 * FW + x1a;   // ch0
    const float* b1 = b0 + (size_t)FH * FW;              // ch1

    float4 regs[10];
    int vrow[10], vc4[10];
    bool vok[10];
    #pragma unroll
    for (int k = 0; k < 10; ++k) {
        const int v = t + k * 256;
        const int r = v / 25;
        vrow[k] = r;
        vc4[k]  = v - r * 25;
        vok[k]  = (v < 2400) && (r < h) && (vc4[k] < wvec);
        regs[k] = vok[k] ? ((const float4*)(b0 + (size_t)r * FW))[vc4[k]]
                         : make_float4(0.f, 0.f, 0.f, 0.f);
    }
    #pragma unroll
    for (int k = 0; k < 10; ++k)
        if (vok[k]) ((float4*)&lds[vrow[k] * LROW])[vc4[k]] = regs[k];
    __syncthreads();

    // ch1 loads in flight while ch0 bin-max runs
    #pragma unroll
    for (int k = 0; k < 10; ++k)
        regs[k] = vok[k] ? ((const float4*)(b1 + (size_t)vrow[k] * FW))[vc4[k]]
                         : make_float4(0.f, 0.f, 0.f, 0.f);

    if (t < 196) {
        const float m = binmax();
        if (s == 0) pooled[o] = m;
    }
    __syncthreads();   // ch0 LDS reads done before overwrite

    #pragma unroll
    for (int k = 0; k < 10; ++k)
        if (vok[k]) ((float4*)&lds[vrow[k] * LROW])[vc4[k]] = regs[k];
    __syncthreads();

    if (t < 196) {
        const float m = binmax();
        if (s == 0) pooled[49 + o] = m;
    }
    __syncthreads();

    // ---- FC (98 -> 4), 32 lanes per output, prefetched weights
    if (t < 128) {
        const int lane = t & 31;
        float acc = 0.f;
        #pragma unroll
        for (int k = 0; k < 4; ++k) {
            const int idx = lane + 32 * k;
            acc = fmaf(idx < 98 ? pooled[idx] : 0.f, wpre[k], acc);
        }
        #pragma unroll
        for (int mm = 16; mm; mm >>= 1)
            acc += __shfl_xor(acc, mm, 64);   // mask<32 stays within 32-lane group
        if (lane == 0) delta[t >> 5] = fmaxf(acc + bias, 0.f);
    }
    __syncthreads();

    if (t < 6)
        out[n * 6 + t] = bx + (t >= 2 ? delta[t - 2] : 0.f);
}

extern "C" void kernel_launch(void* const* d_in, const int* in_sizes, int n_in,
                              void* d_out, int out_size, void* d_ws, size_t ws_size,
                              hipStream_t stream) {
    const float* feature = (const float*)d_in[0];  // [1,2,2048,2048] fp32
    const float* boxes   = (const float*)d_in[1];  // [N,6] fp32
    const int*   coords  = (const int*)d_in[2];    // [N,4] int32
    const float* fc_w    = (const float*)d_in[3];  // [4,98] fp32
    const float* fc_b    = (const float*)d_in[4];  // [4] fp32
    float* out = (float*)d_out;                    // [N,6] fp32

    const int N = in_sizes[2] / 4;
    roi_pool_fc_kernel<<<N, 256, 0, stream>>>(feature, boxes, coords, fc_w, fc_b, out, N);
}

// Round 6
// 85.598 us; speedup vs baseline: 1.2574x; 1.2574x over previous
//
#include <hip/hip_runtime.h>
#include <float.h>

#define POOL 7
#define FW 2048
#define FH 2048
#define CROP 96
#define LROW 100   // floats per LDS row = 25 float4 EXACTLY -> LDS addr = 16*v (contiguous, DMA-compatible)

// async global->LDS DMA, 16B per lane, wave-uniform LDS base + lane*16
#define GLD16(gp, lp) __builtin_amdgcn_global_load_lds( \
    (const __attribute__((address_space(1))) void*)(gp), \
    (__attribute__((address_space(3))) void*)(lp), 16, 0, 0)

// One block per box.
//  ch0 window (rows<h, vec4 groups<wvec) DMA'd straight to LDS (global_load_lds),
//  ch1 issued into regs immediately after -> both HBM windows in flight at once.
//  Bin-max from LDS (4 lanes/output row-split + shfl combine), runtime bounds
//  (compile-time unroll caused spills in R5 -- keep loops small).
//  98->4 FC (32 lanes/output, prefetched weights) + ReLU + add into boxes row.
__global__ __launch_bounds__(256, 4) void roi_pool_fc_kernel(
    const float* __restrict__ feature,   // [2, 2048, 2048]
    const float* __restrict__ boxes,     // [N, 6]
    const int*   __restrict__ coords,    // [N, 4] (y1, x1, y2, x2)
    const float* __restrict__ fc_w,      // [4, 98]
    const float* __restrict__ fc_b,      // [4]
    float* __restrict__ out,             // [N, 6]
    int N)
{
    const int n = blockIdx.x;
    const int t = threadIdx.x;

    __shared__ float lds[CROP * LROW];   // 38,400 B -> 4 blocks/CU (1024 blocks = 1 round)
    __shared__ float pooled[98];         // channel-major: c*49 + i*7 + j
    __shared__ float delta[4];

    const int4 cd = ((const int4*)coords)[n];   // uniform -> s_load
    const int y1 = cd.x;
    const int x1 = cd.y;
    const int h  = cd.z - y1;   // 7 <= h <= 96
    const int w  = cd.w - x1;   // 7 <= w <= 96

    const int x1a  = x1 & ~3;              // 16B-aligned window start
    const int off  = x1 - x1a;             // 0..3
    const int wvec = (w + off + 3) >> 2;   // float4 groups needed per row (<=25)

    // small prefetches (cheap; hidden under the staging window)
    float wpre[4] = {0.f, 0.f, 0.f, 0.f};
    float bias = 0.f;
    if (t < 128) {
        const int oo = t >> 5, lane = t & 31;
        const float* wrow = fc_w + oo * 98;
        #pragma unroll
        for (int k = 0; k < 4; ++k) {
            const int idx = lane + 32 * k;
            if (idx < 98) wpre[k] = wrow[idx];
        }
        if (lane == 0) bias = fc_b[oo];
    }
    const float bx = (t < 6) ? boxes[n * 6 + t] : 0.f;

    // ---- staging: up to 96 rows x 25 vec4 = 2400 vec4s; 10 chunks of 256 lanes.
    const float* b0 = feature + (size_t)y1 * FW + x1a;   // ch0
    const float* b1 = b0 + (size_t)FH * FW;              // ch1
    const int wbase = t & 192;                           // wave_id*64

    int   goff[10];
    bool  vok[10];
    #pragma unroll
    for (int k = 0; k < 10; ++k) {
        const int v = t + k * 256;
        const int r = v / 25;               // const-div -> magic mul
        const int c4 = v - r * 25;
        goff[k] = r * FW + 4 * c4;          // float offset into window
        vok[k]  = (v < 2400) && (r < h) && (c4 < wvec);
    }

    // ch0: async DMA straight into LDS (LDS addr = 16*v, wave-uniform base + lane*16)
    #pragma unroll
    for (int k = 0; k < 10; ++k) {
        char* lbase = (char*)lds + 16 * (wbase + k * 256);
        if (vok[k]) GLD16(b0 + goff[k], lbase);
    }
    // ch1: issue immediately -> both channels' HBM windows in flight concurrently
    float4 regs[10];
    #pragma unroll
    for (int k = 0; k < 10; ++k)
        regs[k] = vok[k] ? *(const float4*)(b1 + goff[k])
                         : make_float4(0.f, 0.f, 0.f, 0.f);

    // compute-phase mapping: t -> (output o, row-split slot s)
    const int o = t >> 2;           // 0..48 for t < 196
    const int s = t & 3;
    const int i = o / 7;
    const int j = o % 7;
    int sr = 0, er = 0, sc = 0, ec = 0, sc4 = 0, ec4 = 0;
    if (t < 196) {
        sr  = (i * h) / POOL;
        er  = ((i + 1) * h + POOL - 1) / POOL;          // er <= h
        sc  = (j * w) / POOL + off;
        ec  = ((j + 1) * w + POOL - 1) / POOL + off;    // ec <= 4*wvec
        sc4 = sc >> 2;
        ec4 = (ec + 3) >> 2;                            // reads stay < wvec (staged)
    }

    __syncthreads();   // drains DMA (vmcnt) + all lanes ready

    // Phase 1: bin max ch0 from LDS (runtime bounds -- no spill)
    if (t < 196) {
        float m = -FLT_MAX;
        for (int r = sr + s; r < er; r += 4) {
            const float4* rowp = (const float4*)(lds + r * LROW);
            for (int c4 = sc4; c4 < ec4; ++c4) {
                const float4 v = rowp[c4];
                const int b = c4 * 4;
                m = fmaxf(m, (b + 0 >= sc && b + 0 < ec) ? v.x : -FLT_MAX);
                m = fmaxf(m, (b + 1 >= sc && b + 1 < ec) ? v.y : -FLT_MAX);
                m = fmaxf(m, (b + 2 >= sc && b + 2 < ec) ? v.z : -FLT_MAX);
                m = fmaxf(m, (b + 3 >= sc && b + 3 < ec) ? v.w : -FLT_MAX);
            }
        }
        m = fmaxf(m, __shfl_xor(m, 1, 64));
        m = fmaxf(m, __shfl_xor(m, 2, 64));
        if (s == 0) pooled[o] = m;
    }
    __syncthreads();   // ch0 LDS reads done before overwrite

    // ch1 regs -> LDS (data long since landed)
    #pragma unroll
    for (int k = 0; k < 10; ++k)
        if (vok[k]) *(float4*)((char*)lds + 16 * (t + k * 256)) = regs[k];
    __syncthreads();

    // Phase 2: bin max ch1
    if (t < 196) {
        float m = -FLT_MAX;
        for (int r = sr + s; r < er; r += 4) {
            const float4* rowp = (const float4*)(lds + r * LROW);
            for (int c4 = sc4; c4 < ec4; ++c4) {
                const float4 v = rowp[c4];
                const int b = c4 * 4;
                m = fmaxf(m, (b + 0 >= sc && b + 0 < ec) ? v.x : -FLT_MAX);
                m = fmaxf(m, (b + 1 >= sc && b + 1 < ec) ? v.y : -FLT_MAX);
                m = fmaxf(m, (b + 2 >= sc && b + 2 < ec) ? v.z : -FLT_MAX);
                m = fmaxf(m, (b + 3 >= sc && b + 3 < ec) ? v.w : -FLT_MAX);
            }
        }
        m = fmaxf(m, __shfl_xor(m, 1, 64));
        m = fmaxf(m, __shfl_xor(m, 2, 64));
        if (s == 0) pooled[49 + o] = m;
    }
    __syncthreads();

    // Phase 3: FC (98 -> 4), 32 lanes per output, prefetched weights
    if (t < 128) {
        const int lane = t & 31;
        float acc = 0.f;
        #pragma unroll
        for (int k = 0; k < 4; ++k) {
            const int idx = lane + 32 * k;
            acc = fmaf(idx < 98 ? pooled[idx] : 0.f, wpre[k], acc);
        }
        #pragma unroll
        for (int mm = 16; mm; mm >>= 1)
            acc += __shfl_xor(acc, mm, 64);   // masks <32 stay within 32-lane group
        if (lane == 0) delta[t >> 5] = fmaxf(acc + bias, 0.f);
    }
    __syncthreads();

    if (t < 6)
        out[n * 6 + t] = bx + (t >= 2 ? delta[t - 2] : 0.f);
}

extern "C" void kernel_launch(void* const* d_in, const int* in_sizes, int n_in,
                              void* d_out, int out_size, void* d_ws, size_t ws_size,
                              hipStream_t stream) {
    const float* feature = (const float*)d_in[0];  // [1,2,2048,2048] fp32
    const float* boxes   = (const float*)d_in[1];  // [N,6] fp32
    const int*   coords  = (const int*)d_in[2];    // [N,4] int32
    const float* fc_w    = (const float*)d_in[3];  // [4,98] fp32
    const float* fc_b    = (const float*)d_in[4];  // [4] fp32
    float* out = (float*)d_out;                    // [N,6] fp32

    const int N = in_sizes[2] / 4;
    roi_pool_fc_kernel<<<N, 256, 0, stream>>>(feature, boxes, coords, fc_w, fc_b, out, N);
}